// Round 9
// baseline (83.539 us; speedup 1.0000x reference)
//
#include <hip/hip_runtime.h>
#include <hip/hip_bf16.h>

typedef __attribute__((ext_vector_type(8))) short short8;
typedef __attribute__((ext_vector_type(4))) float float4v;

#define T_LEN 4096
#define L_LEN 128
#define NWIN  3969
#define CK    128

__device__ __forceinline__ unsigned short f2bf(float f) {
    unsigned u = __float_as_uint(f);
    u += 0x7fffu + ((u >> 16) & 1u);          // RNE
    return (unsigned short)(u >> 16);
}

// 128 blocks x 128 threads: normalize shapelet ck=blockIdx, write B-swizzled
__global__ void prep_sh(const float* __restrict__ sh,
                        unsigned short* __restrict__ wsB) {
    const int ck = blockIdx.x;       // 0..127
    const int l  = threadIdx.x;      // 0..127
    __shared__ float rs[2], rq[2];
    const int lane = l & 63, wv = l >> 6;

    float v = sh[ck * L_LEN + l];
    float s = v, q = v * v;
    #pragma unroll
    for (int off = 32; off >= 1; off >>= 1) {
        s += __shfl_xor(s, off);
        q += __shfl_xor(q, off);
    }
    if (lane == 0) { rs[wv] = s; rq[wv] = q; }
    __syncthreads();
    float sm = rs[0] + rs[1], sq = rq[0] + rq[1];
    float mu  = sm * (1.f / L_LEN);
    float var = fmaxf(sq * (1.f / L_LEN) - mu * mu, 0.f);
    float inv = 1.f / (sqrtf(var) + 1e-6f);
    unsigned short b = f2bf((v - mu) * inv);
    // B-operand fragment order: lane' = qd*16 + n, 8 contiguous bf16
    const int nt = ck >> 4, n = ck & 15;
    const int kt = l >> 5, qd = (l >> 3) & 3, jj = l & 7;
    wsB[((((nt * 4 + kt) * 64) + qd * 16 + n) << 3) + jj] = b;
}

// one block per row; 1024 threads = 16 waves = 4 waves/SIMD (128-reg budget).
// wave (mg = wv&7, nh = wv>>3): windows T0 + mg + 8m (m=0..15), shapelets
// [64*nh, 64*nh+64). Bf = 64 VGPRs/wave, loaded once per row. A-frags are
// single aligned ds_read_b128 from shifted copy (T0+mg)&7.
__global__ __launch_bounds__(1024, 4)
void conv_row(const float* __restrict__ x,
              const unsigned short* __restrict__ wsB,
              float* __restrict__ out) {
    __shared__ alignas(16) unsigned short xb[8][T_LEN]; // 64 KB shifted copies
    __shared__ float sty[T_LEN];                        // 16 KB: 1/(sd*L)
    __shared__ float PSs[513], PQs[513];                // prefix sums @8-elem
    __shared__ float grpS[8], grpQ[8];
    __shared__ float wmax[16][64];                      // 4 KB

    const int tid  = threadIdx.x;
    const int lane = tid & 63;
    const int wv   = tid >> 6;
    const int row  = blockIdx.x;
    const float4* xr4 = (const float4*)(x + row * T_LEN);
    const bool stg = (tid < 512);       // waves 0..7 do staging/scan/stats

    // ---- B fragments -> 64 registers per wave (issued first) ----
    const int mg = wv & 7, nh = wv >> 3;
    short8 Bf[4][4];
    {
        const short8* Bp = (const short8*)wsB;
        #pragma unroll
        for (int nt4 = 0; nt4 < 4; ++nt4)
            #pragma unroll
            for (int kt = 0; kt < 4; ++kt)
                Bf[nt4][kt] = Bp[((nh * 4 + nt4) * 4 + kt) * 64 + lane];
    }

    // ---- stage row (waves 0..7): thread t owns elems [8t,8t+8) ----
    float v[16];
    float s = 0.f, q = 0.f;
    if (stg) {
        float4 a0 = xr4[2 * tid];
        float4 a1 = xr4[2 * tid + 1];
        float4 a2 = make_float4(0.f, 0.f, 0.f, 0.f), a3 = a2;
        if (tid < 511) { a2 = xr4[2 * tid + 2]; a3 = xr4[2 * tid + 3]; }
        v[0]=a0.x; v[1]=a0.y; v[2]=a0.z;  v[3]=a0.w;
        v[4]=a1.x; v[5]=a1.y; v[6]=a1.z;  v[7]=a1.w;
        v[8]=a2.x; v[9]=a2.y; v[10]=a2.z; v[11]=a2.w;
        v[12]=a3.x; v[13]=a3.y; v[14]=a3.z; v[15]=a3.w;

        unsigned short bb[16];
        #pragma unroll
        for (int i = 0; i < 16; ++i) bb[i] = f2bf(v[i]);
        #pragma unroll
        for (int c = 0; c < 8; ++c) {       // copy_c[i] = x[i+c]; aligned b128
            short8 w8;
            #pragma unroll
            for (int j = 0; j < 8; ++j) w8[j] = (short)bb[c + j];
            *(short8*)&xb[c][8 * tid] = w8;
        }

        // seg sums (8 owned elems) + wave-inclusive scan
        #pragma unroll
        for (int i = 0; i < 8; ++i) { s += v[i]; q += v[i] * v[i]; }
        float is = s, iq = q;
        #pragma unroll
        for (int off = 1; off < 64; off <<= 1) {
            float ts = __shfl_up(is, off);
            float tq = __shfl_up(iq, off);
            if (lane >= off) { is += ts; iq += tq; }
        }
        if (lane == 63) { grpS[wv] = is; grpQ[wv] = iq; }
        s = is; q = iq;                      // carry inclusive scan
    }
    __syncthreads();
    if (stg) {
        float ss = s, qq = q;                // inclusive within wave
        // recover own seg sums to make prefix exclusive
        float segs = 0.f, segq = 0.f;
        #pragma unroll
        for (int i = 0; i < 8; ++i) { segs += v[i]; segq += v[i] * v[i]; }
        float os = 0.f, oq = 0.f;
        #pragma unroll
        for (int w = 0; w < 7; ++w) if (w < wv) { os += grpS[w]; oq += grpQ[w]; }
        PSs[tid] = os + ss - segs;           // exclusive prefix at elem 8*tid
        PQs[tid] = oq + qq - segq;
        if (tid == 511) { PSs[512] = os + ss; PQs[512] = oq + qq; }
    }
    __syncthreads();

    // ---- window stats: thread t -> windows [8t, 8t+8), incremental ----
    if (tid < 497) {
        float S = PSs[tid + 16] - PSs[tid];  // sum over [8t, 8t+128)
        float Q = PQs[tid + 16] - PQs[tid];
        float4 b0 = make_float4(0.f, 0.f, 0.f, 0.f), b1 = b0;
        if (tid <= 495) { b0 = xr4[2 * tid + 32]; b1 = xr4[2 * tid + 33]; }
        float xn[8] = {b0.x, b0.y, b0.z, b0.w, b1.x, b1.y, b1.z, b1.w};
        #pragma unroll
        for (int e = 0; e < 8; ++e) {
            int w = 8 * tid + e;
            if (w < NWIN) {
                float mu  = S * (1.f / L_LEN);
                float var = fmaxf(Q * (1.f / L_LEN) - mu * mu, 0.f);
                float sd  = sqrtf(var) + 1e-6f;
                sty[w] = 1.f / (sd * (float)L_LEN);
                S += xn[e] - v[e];
                Q += xn[e] * xn[e] - v[e] * v[e];
            }
        }
    }
    __syncthreads();                         // xb + sty ready

    // ---- chunk loop: 16 MFMA/wave/chunk; pure ds_read_b128 + MFMA ----
    const int abase = (lane & 15) + (lane >> 4);
    const int q4    = (lane >> 4) * 4;
    float vmax[4] = {-1e30f, -1e30f, -1e30f, -1e30f};

    #pragma unroll 1                         // keep acc live-range single-iter
    for (int ii = 0; ii < 32; ++ii) {
        const int ci = (ii + 4 * mg) & 31;                   // wave-staggered
        const int T0 = (ci < 31) ? ci * 128 : (NWIN - 128);  // last overlaps
        const int e0 = T0 + mg;
        const int c  = e0 & 7;
        const int b8 = e0 >> 3;

        float sr[4];
        #pragma unroll
        for (int r = 0; r < 4; ++r) sr[r] = sty[e0 + 8 * (q4 + r)];
        short8 af[4];
        #pragma unroll
        for (int kt = 0; kt < 4; ++kt)
            af[kt] = *(const short8*)&xb[c][8 * (b8 + abase + 4 * kt)];

        float4v acc[4];
        #pragma unroll
        for (int nt4 = 0; nt4 < 4; ++nt4) acc[nt4] = float4v{0.f, 0.f, 0.f, 0.f};

        #pragma unroll
        for (int kt = 0; kt < 4; ++kt)
            #pragma unroll
            for (int nt4 = 0; nt4 < 4; ++nt4)
                acc[nt4] = __builtin_amdgcn_mfma_f32_16x16x32_bf16(
                    af[kt], Bf[nt4][kt], acc[nt4], 0, 0, 0);

        #pragma unroll
        for (int nt4 = 0; nt4 < 4; ++nt4) {
            float m01 = fmaxf(acc[nt4][0] * sr[0], acc[nt4][1] * sr[1]);
            float m23 = fmaxf(acc[nt4][2] * sr[2], acc[nt4][3] * sr[3]);
            vmax[nt4] = fmaxf(vmax[nt4], fmaxf(m01, m23));
        }
    }

    // ---- cross-lane + cross-wave max, direct store ----
    #pragma unroll
    for (int nt4 = 0; nt4 < 4; ++nt4) {
        float vx = vmax[nt4];
        vx = fmaxf(vx, __shfl_xor(vx, 16));
        vx = fmaxf(vx, __shfl_xor(vx, 32));
        if (lane < 16) wmax[wv][nt4 * 16 + lane] = vx;
    }
    __syncthreads();
    if (tid < CK) {
        const int h = tid >> 6, idx = tid & 63;   // ck = 64h + idx
        float m = wmax[8 * h][idx];
        #pragma unroll
        for (int g = 1; g < 8; ++g) m = fmaxf(m, wmax[8 * h + g][idx]);
        out[row * CK + tid] = m;
    }
}

extern "C" void kernel_launch(void* const* d_in, const int* in_sizes, int n_in,
                              void* d_out, int out_size, void* d_ws, size_t ws_size,
                              hipStream_t stream) {
    (void)in_sizes; (void)n_in; (void)out_size; (void)ws_size;
    const float* x  = (const float*)d_in[0];
    const float* sh = (const float*)d_in[1];
    unsigned short* wsB = (unsigned short*)d_ws;   // 32 KB (proven safe)
    float* out = (float*)d_out;

    prep_sh<<<128, 128, 0, stream>>>(sh, wsB);
    conv_row<<<256, 1024, 0, stream>>>(x, wsB, out);
}